// Round 2
// baseline (1843.987 us; speedup 1.0000x reference)
//
#include <hip/hip_runtime.h>

#define N_NODES 20000
#define N_EDGES 320000
#define X_DIM 128
#define EDGE_DIM 64
#define HIDDEN 256
#define N_GRAPHS 64
#define LAYERS 3

#define NPB 8     // nodes per block (node_proj)
#define RPB 16    // rows per block (mlp)
#define GNPB 16   // nodes per block (gather)
#define ECH 32    // edge chunk staged in LDS (gather)
#define NBLK ((N_NODES + 255) / 256)   // 79 scan blocks

// ---------------- CSR build (once per launch) ----------------

__global__ __launch_bounds__(256) void deg_kernel(const int* __restrict__ ei,
                                                  int* __restrict__ deg)
{
    int e = blockIdx.x * 256 + threadIdx.x;
    if (e < N_EDGES) atomicAdd(&deg[ei[N_EDGES + e]], 1);
}

// block-local exclusive scan of deg -> rowptr, block totals -> bsum
__global__ __launch_bounds__(256) void pscan_kernel(const int* __restrict__ deg,
                                                    int* __restrict__ rp,
                                                    int* __restrict__ bsum)
{
    __shared__ int buf[256];
    const int t = threadIdx.x;
    const int i = blockIdx.x * 256 + t;
    int v = (i < N_NODES) ? deg[i] : 0;
    buf[t] = v;
    __syncthreads();
    for (int off = 1; off < 256; off <<= 1) {
        int a = (t >= off) ? buf[t - off] : 0;
        __syncthreads();
        buf[t] += a;
        __syncthreads();
    }
    if (i < N_NODES) rp[i] = buf[t] - v;
    if (t == 255) bsum[blockIdx.x] = buf[255];
}

// scan the 79 block sums
__global__ __launch_bounds__(128) void bscan_kernel(const int* __restrict__ bsum,
                                                    int* __restrict__ boff)
{
    __shared__ int buf[128];
    const int t = threadIdx.x;
    int v = (t < NBLK) ? bsum[t] : 0;
    buf[t] = v;
    __syncthreads();
    for (int off = 1; off < 128; off <<= 1) {
        int a = (t >= off) ? buf[t - off] : 0;
        __syncthreads();
        buf[t] += a;
        __syncthreads();
    }
    if (t < NBLK) boff[t] = buf[t] - v;
}

__global__ __launch_bounds__(256) void addoff_kernel(int* __restrict__ rp,
                                                     const int* __restrict__ boff)
{
    const int i = blockIdx.x * 256 + threadIdx.x;
    if (i < N_NODES) rp[i] += boff[blockIdx.x];
    if (i == 0) rp[N_NODES] = N_EDGES;  // total degree is always N_EDGES
}

__global__ __launch_bounds__(256) void scatter_kernel(const int* __restrict__ ei,
                                                      const int* __restrict__ rp,
                                                      int* __restrict__ cursor,
                                                      int* __restrict__ perm)
{
    const int e = blockIdx.x * 256 + threadIdx.x;
    if (e < N_EDGES) {
        const int d = ei[N_EDGES + e];
        const int pos = atomicAdd(&cursor[d], 1);
        perm[rp[d] + pos] = e;
    }
}

// ---------------- model kernels ----------------

// h[i] = x[i] @ xW + xb
__global__ __launch_bounds__(256) void node_proj_kernel(
    const float* __restrict__ x, const float* __restrict__ W,
    const float* __restrict__ b, float* __restrict__ h)
{
    const int t = threadIdx.x;
    const int row0 = blockIdx.x * NPB;
    __shared__ float xs[NPB][X_DIM];
    for (int idx = t; idx < NPB * X_DIM; idx += 256)
        xs[idx / X_DIM][idx % X_DIM] = x[(size_t)row0 * X_DIM + idx];
    __syncthreads();
    float acc[NPB];
    const float bt = b[t];
#pragma unroll
    for (int r = 0; r < NPB; r++) acc[r] = bt;
    for (int k = 0; k < X_DIM; k++) {
        const float wv = W[k * HIDDEN + t];
#pragma unroll
        for (int r = 0; r < NPB; r++) acc[r] += xs[r][k] * wv;
    }
#pragma unroll
    for (int r = 0; r < NPB; r++)
        h[(size_t)(row0 + r) * HIDDEN + t] = acc[r];
}

// pull aggregation: z[n] = h[n] + sum_{e: dst=n} relu(h[src[e]] + ea[e]@eW + eb)
__global__ __launch_bounds__(256) void gather_kernel(
    const float* __restrict__ ea, const int* __restrict__ ei,
    const float* __restrict__ W, const float* __restrict__ b,
    const float* __restrict__ h, const int* __restrict__ rowptr,
    const int* __restrict__ perm, float* __restrict__ z)
{
    const int t = threadIdx.x;
    const int n0 = blockIdx.x * GNPB;
    // this thread's column of eW, held in registers
    float wcol[EDGE_DIM];
#pragma unroll
    for (int k = 0; k < EDGE_DIM; k++) wcol[k] = W[k * HIDDEN + t];
    const float bt = b[t];

    __shared__ float4 es[ECH][EDGE_DIM / 4];
    __shared__ int s_src[ECH];

    for (int ni = 0; ni < GNPB; ni++) {
        const int n = n0 + ni;
        const int rs = rowptr[n], re = rowptr[n + 1];
        float acc = h[(size_t)n * HIDDEN + t];
        for (int cs = rs; cs < re; cs += ECH) {
            const int cnt = min(ECH, re - cs);
            __syncthreads();  // protect LDS reuse from previous chunk
            for (int idx = t; idx < cnt * EDGE_DIM; idx += 256) {
                const int j = idx >> 6, k = idx & 63;
                ((float*)es)[j * EDGE_DIM + k] =
                    ea[(size_t)perm[cs + j] * EDGE_DIM + k];
            }
            if (t < cnt) s_src[t] = ei[perm[cs + t]];
            __syncthreads();
            for (int j = 0; j < cnt; j++) {
                float m = bt + h[(size_t)s_src[j] * HIDDEN + t];
#pragma unroll
                for (int k4 = 0; k4 < EDGE_DIM / 4; k4++) {
                    const float4 v = es[j][k4];  // LDS broadcast
                    m += v.x * wcol[4 * k4 + 0];
                    m += v.y * wcol[4 * k4 + 1];
                    m += v.z * wcol[4 * k4 + 2];
                    m += v.w * wcol[4 * k4 + 3];
                }
                acc += m > 0.f ? m : 0.f;
            }
        }
        z[(size_t)n * HIDDEN + t] = acc;
    }
}

// h = relu(relu(z@W1+b1)@W2+b2)   (z already includes h+agg)
__global__ __launch_bounds__(256) void mlp_kernel(
    const float* __restrict__ W1, const float* __restrict__ b1,
    const float* __restrict__ W2, const float* __restrict__ b2,
    float* __restrict__ h, const float* __restrict__ z)
{
    const int t = threadIdx.x;
    const int row0 = blockIdx.x * RPB;
    __shared__ float zs[RPB][HIDDEN];
    __shared__ float ts[RPB][HIDDEN];
#pragma unroll
    for (int r = 0; r < RPB; r++)
        zs[r][t] = z[(size_t)(row0 + r) * HIDDEN + t];
    __syncthreads();
    float acc[RPB];
    const float bt1 = b1[t];
#pragma unroll
    for (int r = 0; r < RPB; r++) acc[r] = bt1;
    for (int k = 0; k < HIDDEN; k++) {
        const float wv = W1[k * HIDDEN + t];
#pragma unroll
        for (int r = 0; r < RPB; r++) acc[r] += zs[r][k] * wv;
    }
    __syncthreads();
#pragma unroll
    for (int r = 0; r < RPB; r++) ts[r][t] = acc[r] > 0.f ? acc[r] : 0.f;
    __syncthreads();
    const float bt2 = b2[t];
#pragma unroll
    for (int r = 0; r < RPB; r++) acc[r] = bt2;
    for (int k = 0; k < HIDDEN; k++) {
        const float wv = W2[k * HIDDEN + t];
#pragma unroll
        for (int r = 0; r < RPB; r++) acc[r] += ts[r][k] * wv;
    }
#pragma unroll
    for (int r = 0; r < RPB; r++) {
        const float v = acc[r];
        h[(size_t)(row0 + r) * HIDDEN + t] = v > 0.f ? v : 0.f;
    }
}

// mean pool per graph; batch_ids sorted -> binary search bounds
__global__ __launch_bounds__(256) void pool_kernel(
    const float* __restrict__ h, const int* __restrict__ bid,
    float* __restrict__ gout)
{
    const int g = blockIdx.x;
    const int t = threadIdx.x;
    int lo = 0, hi = N_NODES;
    while (lo < hi) { int mid = (lo + hi) >> 1; if (bid[mid] < g) lo = mid + 1; else hi = mid; }
    const int start = lo;
    hi = N_NODES;
    while (lo < hi) { int mid = (lo + hi) >> 1; if (bid[mid] < g + 1) lo = mid + 1; else hi = mid; }
    const int end = lo;
    float s = 0.f;
    for (int i = start; i < end; i++) s += h[(size_t)i * HIDDEN + t];
    const float cnt = (float)(end - start);
    gout[g * HIDDEN + t] = s / (cnt > 1.f ? cnt : 1.f);
}

// out = normalize(relu(g@oW1+ob1)@oW2+ob2)
__global__ __launch_bounds__(256) void head_kernel(
    const float* __restrict__ gin, const float* __restrict__ W1,
    const float* __restrict__ b1, const float* __restrict__ W2,
    const float* __restrict__ b2, float* __restrict__ out)
{
    const int g = blockIdx.x;
    const int t = threadIdx.x;
    __shared__ float gs[HIDDEN];
    __shared__ float t1[HIDDEN];
    __shared__ float red[256];
    gs[t] = gin[g * HIDDEN + t];
    __syncthreads();
    float acc = b1[t];
    for (int k = 0; k < HIDDEN; k++) acc += gs[k] * W1[k * HIDDEN + t];
    t1[t] = acc > 0.f ? acc : 0.f;
    __syncthreads();
    float acc2 = b2[t];
    for (int k = 0; k < HIDDEN; k++) acc2 += t1[k] * W2[k * HIDDEN + t];
    red[t] = acc2 * acc2;
    __syncthreads();
    for (int s = 128; s > 0; s >>= 1) {
        if (t < s) red[t] += red[t + s];
        __syncthreads();
    }
    float norm = sqrtf(red[0]);
    norm = norm > 1e-12f ? norm : 1e-12f;
    out[g * HIDDEN + t] = acc2 / norm;
}

extern "C" void kernel_launch(void* const* d_in, const int* in_sizes, int n_in,
                              void* d_out, int out_size, void* d_ws, size_t ws_size,
                              hipStream_t stream)
{
    const float* x   = (const float*)d_in[0];
    const int*   ei  = (const int*)d_in[1];
    const float* ea  = (const float*)d_in[2];
    const int*   bid = (const int*)d_in[3];
    const float* xW  = (const float*)d_in[4];
    const float* xb  = (const float*)d_in[5];
    const float* eW  = (const float*)d_in[6];
    const float* eb  = (const float*)d_in[7];
    const float* W1  = (const float*)d_in[8];
    const float* b1  = (const float*)d_in[9];
    const float* W2  = (const float*)d_in[10];
    const float* b2  = (const float*)d_in[11];
    const float* oW1 = (const float*)d_in[12];
    const float* ob1 = (const float*)d_in[13];
    const float* oW2 = (const float*)d_in[14];
    const float* ob2 = (const float*)d_in[15];
    float* out = (float*)d_out;

    // workspace layout
    float* h     = (float*)d_ws;                          // 20000*256
    float* z     = h + (size_t)N_NODES * HIDDEN;          // 20000*256
    float* gpool = z + (size_t)N_NODES * HIDDEN;          // 64*256
    int*   deg    = (int*)(gpool + N_GRAPHS * HIDDEN);    // 20000
    int*   rowptr = deg + N_NODES;                        // 20001
    int*   cursor = rowptr + (N_NODES + 1);               // 20000
    int*   bsum   = cursor + N_NODES;                     // NBLK
    int*   boff   = bsum + NBLK;                          // NBLK
    int*   perm   = boff + NBLK;                          // 320000

    // CSR build (reused across all 3 layers)
    hipMemsetAsync(deg, 0, N_NODES * sizeof(int), stream);
    hipMemsetAsync(cursor, 0, N_NODES * sizeof(int), stream);
    deg_kernel<<<(N_EDGES + 255) / 256, 256, 0, stream>>>(ei, deg);
    pscan_kernel<<<NBLK, 256, 0, stream>>>(deg, rowptr, bsum);
    bscan_kernel<<<1, 128, 0, stream>>>(bsum, boff);
    addoff_kernel<<<NBLK, 256, 0, stream>>>(rowptr, boff);
    scatter_kernel<<<(N_EDGES + 255) / 256, 256, 0, stream>>>(ei, rowptr, cursor, perm);

    node_proj_kernel<<<N_NODES / NPB, 256, 0, stream>>>(x, xW, xb, h);
    for (int l = 0; l < LAYERS; l++) {
        gather_kernel<<<N_NODES / GNPB, 256, 0, stream>>>(
            ea, ei, eW + (size_t)l * EDGE_DIM * HIDDEN, eb + l * HIDDEN,
            h, rowptr, perm, z);
        mlp_kernel<<<N_NODES / RPB, 256, 0, stream>>>(
            W1 + (size_t)l * HIDDEN * HIDDEN, b1 + l * HIDDEN,
            W2 + (size_t)l * HIDDEN * HIDDEN, b2 + l * HIDDEN, h, z);
    }
    pool_kernel<<<N_GRAPHS, 256, 0, stream>>>(h, bid, gpool);
    head_kernel<<<N_GRAPHS, 256, 0, stream>>>(gpool, oW1, ob1, oW2, ob2, out);
}

// Round 3
// 1109.709 us; speedup vs baseline: 1.6617x; 1.6617x over previous
//
#include <hip/hip_runtime.h>

#define N_NODES 20000
#define N_EDGES 320000
#define X_DIM 128
#define EDGE_DIM 64
#define HIDDEN 256
#define N_GRAPHS 64
#define LAYERS 3

#define NPB 8     // nodes per block (node_proj)
#define RPB 16    // rows per block (mlp)
#define EB 32     // edges per block (edge_mfma)
#define NBLK ((N_NODES + 255) / 256)   // 79 scan blocks

typedef __attribute__((ext_vector_type(8))) short short8;
typedef __attribute__((ext_vector_type(4))) float floatx4;

__device__ __forceinline__ unsigned short f2bf(float f) {
    union { float f; unsigned u; } v; v.f = f;
    return (unsigned short)((v.u + 0x7FFFu + ((v.u >> 16) & 1u)) >> 16);
}

// ---------------- CSR build (once per launch) ----------------

__global__ __launch_bounds__(256) void deg_kernel(const int* __restrict__ ei,
                                                  int* __restrict__ deg)
{
    int e = blockIdx.x * 256 + threadIdx.x;
    if (e < N_EDGES) atomicAdd(&deg[ei[N_EDGES + e]], 1);
}

__global__ __launch_bounds__(256) void pscan_kernel(const int* __restrict__ deg,
                                                    int* __restrict__ rp,
                                                    int* __restrict__ bsum)
{
    __shared__ int buf[256];
    const int t = threadIdx.x;
    const int i = blockIdx.x * 256 + t;
    int v = (i < N_NODES) ? deg[i] : 0;
    buf[t] = v;
    __syncthreads();
    for (int off = 1; off < 256; off <<= 1) {
        int a = (t >= off) ? buf[t - off] : 0;
        __syncthreads();
        buf[t] += a;
        __syncthreads();
    }
    if (i < N_NODES) rp[i] = buf[t] - v;
    if (t == 255) bsum[blockIdx.x] = buf[255];
}

__global__ __launch_bounds__(128) void bscan_kernel(const int* __restrict__ bsum,
                                                    int* __restrict__ boff)
{
    __shared__ int buf[128];
    const int t = threadIdx.x;
    int v = (t < NBLK) ? bsum[t] : 0;
    buf[t] = v;
    __syncthreads();
    for (int off = 1; off < 128; off <<= 1) {
        int a = (t >= off) ? buf[t - off] : 0;
        __syncthreads();
        buf[t] += a;
        __syncthreads();
    }
    if (t < NBLK) boff[t] = buf[t] - v;
}

__global__ __launch_bounds__(256) void addoff_kernel(int* __restrict__ rp,
                                                     const int* __restrict__ boff)
{
    const int i = blockIdx.x * 256 + threadIdx.x;
    if (i < N_NODES) rp[i] += boff[blockIdx.x];
    if (i == 0) rp[N_NODES] = N_EDGES;
}

__global__ __launch_bounds__(256) void scatter_kernel(const int* __restrict__ ei,
                                                      const int* __restrict__ rp,
                                                      int* __restrict__ cursor,
                                                      int* __restrict__ perm)
{
    const int e = blockIdx.x * 256 + threadIdx.x;
    if (e < N_EDGES) {
        const int d = ei[N_EDGES + e];
        const int pos = atomicAdd(&cursor[d], 1);
        perm[rp[d] + pos] = e;
    }
}

// weights fp32 -> bf16
__global__ __launch_bounds__(256) void cvtw_kernel(const float* __restrict__ w,
                                                   unsigned short* __restrict__ wb, int n)
{
    int i = blockIdx.x * 256 + threadIdx.x;
    if (i < n) wb[i] = f2bf(w[i]);
}

// ---------------- model kernels ----------------

// h[i] = x[i] @ xW + xb ; zero z for layer 0
__global__ __launch_bounds__(256) void node_proj_kernel(
    const float* __restrict__ x, const float* __restrict__ W,
    const float* __restrict__ b, float* __restrict__ h, float* __restrict__ z)
{
    const int t = threadIdx.x;
    const int row0 = blockIdx.x * NPB;
    __shared__ float xs[NPB][X_DIM];
    for (int idx = t; idx < NPB * X_DIM; idx += 256)
        xs[idx / X_DIM][idx % X_DIM] = x[(size_t)row0 * X_DIM + idx];
    __syncthreads();
    float acc[NPB];
    const float bt = b[t];
#pragma unroll
    for (int r = 0; r < NPB; r++) acc[r] = bt;
    for (int k = 0; k < X_DIM; k++) {
        const float wv = W[k * HIDDEN + t];
#pragma unroll
        for (int r = 0; r < NPB; r++) acc[r] += xs[r][k] * wv;
    }
#pragma unroll
    for (int r = 0; r < NPB; r++) {
        h[(size_t)(row0 + r) * HIDDEN + t] = acc[r];
        z[(size_t)(row0 + r) * HIDDEN + t] = 0.f;
    }
}

// edge phase: z[dst] += relu(h[src] + ea@eW + eb), edges dst-sorted via perm.
// proj via bf16 MFMA; segmented-sum epilogue, few atomics per block.
__global__ __launch_bounds__(256) void edge_mfma_kernel(
    const float* __restrict__ ea, const int* __restrict__ ei,
    const unsigned short* __restrict__ Wb,  // [64][256] bf16
    const float* __restrict__ b,
    const float* __restrict__ h, const int* __restrict__ perm,
    float* __restrict__ z)
{
    const int t = threadIdx.x;
    const int lane = t & 63;
    const int wv = t >> 6;          // wave 0..3 -> channels [wv*64, wv*64+64)
    const int q = lane >> 4;
    const int m15 = lane & 15;
    const int e0 = blockIdx.x * EB;
    const int cbase = wv * 64;

    __shared__ __align__(16) unsigned short sa[EB][72];  // ea bf16, padded rows
    __shared__ float msg[EB][260];                       // proj fp32, padded
    __shared__ int s_perm[EB], s_src[EB], s_dst[EB];

    if (t < EB) {
        const int p = perm[e0 + t];
        s_perm[t] = p;
        s_src[t] = ei[p];
        s_dst[t] = ei[N_EDGES + p];
    }
    __syncthreads();

    // stage ea rows (gathered, 256B contiguous per row) -> bf16 LDS
    {
        const int r = t >> 3, seg = t & 7;
        const float* srcp = ea + (size_t)s_perm[r] * EDGE_DIM + seg * 8;
        const float4 v0 = *(const float4*)(srcp);
        const float4 v1 = *(const float4*)(srcp + 4);
        unsigned short* dp = &sa[r][seg * 8];
        dp[0] = f2bf(v0.x); dp[1] = f2bf(v0.y); dp[2] = f2bf(v0.z); dp[3] = f2bf(v0.w);
        dp[4] = f2bf(v1.x); dp[5] = f2bf(v1.y); dp[6] = f2bf(v1.z); dp[7] = f2bf(v1.w);
    }

    // B fragments: B[k = kk*32 + q*8 + j][n = cbase + nt*16 + m15]
    short8 bf[4][2];
#pragma unroll
    for (int nt = 0; nt < 4; nt++)
#pragma unroll
        for (int kk = 0; kk < 2; kk++) {
            const int n = cbase + nt * 16 + m15;
#pragma unroll
            for (int j = 0; j < 8; j++)
                bf[nt][kk][j] = (short)Wb[(kk * 32 + q * 8 + j) * HIDDEN + n];
        }
    __syncthreads();

    floatx4 acc[2][4];
#pragma unroll
    for (int mt = 0; mt < 2; mt++)
#pragma unroll
        for (int nt = 0; nt < 4; nt++)
            acc[mt][nt] = (floatx4){0.f, 0.f, 0.f, 0.f};

#pragma unroll
    for (int kk = 0; kk < 2; kk++) {
        const short8 a0 = *(const short8*)&sa[m15][kk * 32 + q * 8];
        const short8 a1 = *(const short8*)&sa[16 + m15][kk * 32 + q * 8];
#pragma unroll
        for (int nt = 0; nt < 4; nt++) {
            acc[0][nt] = __builtin_amdgcn_mfma_f32_16x16x32_bf16(a0, bf[nt][kk], acc[0][nt], 0, 0, 0);
            acc[1][nt] = __builtin_amdgcn_mfma_f32_16x16x32_bf16(a1, bf[nt][kk], acc[1][nt], 0, 0, 0);
        }
    }

    // C layout: edge = mt*16 + q*4 + r, ch = cbase + nt*16 + m15
#pragma unroll
    for (int mt = 0; mt < 2; mt++)
#pragma unroll
        for (int nt = 0; nt < 4; nt++)
#pragma unroll
            for (int r = 0; r < 4; r++)
                msg[mt * 16 + q * 4 + r][cbase + nt * 16 + m15] = acc[mt][nt][r];
    __syncthreads();

    // channel phase: thread t owns channel t; segmented sum over sorted dst
    const float bt = b[t];
    float s = 0.f;
    int prev = s_dst[0];
#pragma unroll
    for (int e = 0; e < EB; e++) {
        const int d = s_dst[e];
        if (d != prev) {
            atomicAdd(&z[(size_t)prev * HIDDEN + t], s);
            s = 0.f; prev = d;
        }
        const float m = msg[e][t] + bt + h[(size_t)s_src[e] * HIDDEN + t];
        s += m > 0.f ? m : 0.f;
    }
    atomicAdd(&z[(size_t)prev * HIDDEN + t], s);
}

// h = relu(relu((h+z)@W1+b1)@W2+b2); re-zero z for next layer
__global__ __launch_bounds__(256) void mlp_kernel(
    const float* __restrict__ W1, const float* __restrict__ b1,
    const float* __restrict__ W2, const float* __restrict__ b2,
    float* __restrict__ h, float* __restrict__ z)
{
    const int t = threadIdx.x;
    const int row0 = blockIdx.x * RPB;
    __shared__ float zs[RPB][HIDDEN];
    __shared__ float ts[RPB][HIDDEN];
#pragma unroll
    for (int r = 0; r < RPB; r++) {
        const size_t idx = (size_t)(row0 + r) * HIDDEN + t;
        zs[r][t] = h[idx] + z[idx];
        z[idx] = 0.f;
    }
    __syncthreads();
    float acc[RPB];
    const float bt1 = b1[t];
#pragma unroll
    for (int r = 0; r < RPB; r++) acc[r] = bt1;
    for (int k = 0; k < HIDDEN; k++) {
        const float wv = W1[k * HIDDEN + t];
#pragma unroll
        for (int r = 0; r < RPB; r++) acc[r] += zs[r][k] * wv;
    }
    __syncthreads();
#pragma unroll
    for (int r = 0; r < RPB; r++) ts[r][t] = acc[r] > 0.f ? acc[r] : 0.f;
    __syncthreads();
    const float bt2 = b2[t];
#pragma unroll
    for (int r = 0; r < RPB; r++) acc[r] = bt2;
    for (int k = 0; k < HIDDEN; k++) {
        const float wv = W2[k * HIDDEN + t];
#pragma unroll
        for (int r = 0; r < RPB; r++) acc[r] += ts[r][k] * wv;
    }
#pragma unroll
    for (int r = 0; r < RPB; r++) {
        const float v = acc[r];
        h[(size_t)(row0 + r) * HIDDEN + t] = v > 0.f ? v : 0.f;
    }
}

__global__ __launch_bounds__(256) void pool_kernel(
    const float* __restrict__ h, const int* __restrict__ bid,
    float* __restrict__ gout)
{
    const int g = blockIdx.x;
    const int t = threadIdx.x;
    int lo = 0, hi = N_NODES;
    while (lo < hi) { int mid = (lo + hi) >> 1; if (bid[mid] < g) lo = mid + 1; else hi = mid; }
    const int start = lo;
    hi = N_NODES;
    while (lo < hi) { int mid = (lo + hi) >> 1; if (bid[mid] < g + 1) lo = mid + 1; else hi = mid; }
    const int end = lo;
    float s = 0.f;
    for (int i = start; i < end; i++) s += h[(size_t)i * HIDDEN + t];
    const float cnt = (float)(end - start);
    gout[g * HIDDEN + t] = s / (cnt > 1.f ? cnt : 1.f);
}

__global__ __launch_bounds__(256) void head_kernel(
    const float* __restrict__ gin, const float* __restrict__ W1,
    const float* __restrict__ b1, const float* __restrict__ W2,
    const float* __restrict__ b2, float* __restrict__ out)
{
    const int g = blockIdx.x;
    const int t = threadIdx.x;
    __shared__ float gs[HIDDEN];
    __shared__ float t1[HIDDEN];
    __shared__ float red[256];
    gs[t] = gin[g * HIDDEN + t];
    __syncthreads();
    float acc = b1[t];
    for (int k = 0; k < HIDDEN; k++) acc += gs[k] * W1[k * HIDDEN + t];
    t1[t] = acc > 0.f ? acc : 0.f;
    __syncthreads();
    float acc2 = b2[t];
    for (int k = 0; k < HIDDEN; k++) acc2 += t1[k] * W2[k * HIDDEN + t];
    red[t] = acc2 * acc2;
    __syncthreads();
    for (int s = 128; s > 0; s >>= 1) {
        if (t < s) red[t] += red[t + s];
        __syncthreads();
    }
    float norm = sqrtf(red[0]);
    norm = norm > 1e-12f ? norm : 1e-12f;
    out[g * HIDDEN + t] = acc2 / norm;
}

extern "C" void kernel_launch(void* const* d_in, const int* in_sizes, int n_in,
                              void* d_out, int out_size, void* d_ws, size_t ws_size,
                              hipStream_t stream)
{
    const float* x   = (const float*)d_in[0];
    const int*   ei  = (const int*)d_in[1];
    const float* ea  = (const float*)d_in[2];
    const int*   bid = (const int*)d_in[3];
    const float* xW  = (const float*)d_in[4];
    const float* xb  = (const float*)d_in[5];
    const float* eW  = (const float*)d_in[6];
    const float* eb  = (const float*)d_in[7];
    const float* W1  = (const float*)d_in[8];
    const float* b1  = (const float*)d_in[9];
    const float* W2  = (const float*)d_in[10];
    const float* b2  = (const float*)d_in[11];
    const float* oW1 = (const float*)d_in[12];
    const float* ob1 = (const float*)d_in[13];
    const float* oW2 = (const float*)d_in[14];
    const float* ob2 = (const float*)d_in[15];
    float* out = (float*)d_out;

    // workspace layout
    float* h     = (float*)d_ws;                          // 20000*256
    float* z     = h + (size_t)N_NODES * HIDDEN;          // 20000*256
    float* gpool = z + (size_t)N_NODES * HIDDEN;          // 64*256
    int*   deg    = (int*)(gpool + N_GRAPHS * HIDDEN);    // 20000
    int*   rowptr = deg + N_NODES;                        // 20001
    int*   cursor = rowptr + (N_NODES + 1);               // 20000
    int*   bsum   = cursor + N_NODES;                     // NBLK
    int*   boff   = bsum + NBLK;                          // NBLK
    int*   perm   = boff + NBLK;                          // 320000
    unsigned short* eWb = (unsigned short*)(perm + N_EDGES); // 3*64*256 bf16

    // CSR build (dst-sorted edge permutation, reused across layers)
    hipMemsetAsync(deg, 0, N_NODES * sizeof(int), stream);
    hipMemsetAsync(cursor, 0, N_NODES * sizeof(int), stream);
    deg_kernel<<<(N_EDGES + 255) / 256, 256, 0, stream>>>(ei, deg);
    pscan_kernel<<<NBLK, 256, 0, stream>>>(deg, rowptr, bsum);
    bscan_kernel<<<1, 128, 0, stream>>>(bsum, boff);
    addoff_kernel<<<NBLK, 256, 0, stream>>>(rowptr, boff);
    scatter_kernel<<<(N_EDGES + 255) / 256, 256, 0, stream>>>(ei, rowptr, cursor, perm);
    cvtw_kernel<<<(LAYERS * EDGE_DIM * HIDDEN + 255) / 256, 256, 0, stream>>>(
        eW, eWb, LAYERS * EDGE_DIM * HIDDEN);

    node_proj_kernel<<<N_NODES / NPB, 256, 0, stream>>>(x, xW, xb, h, z);
    for (int l = 0; l < LAYERS; l++) {
        edge_mfma_kernel<<<N_EDGES / EB, 256, 0, stream>>>(
            ea, ei, eWb + (size_t)l * EDGE_DIM * HIDDEN, eb + l * HIDDEN,
            h, perm, z);
        mlp_kernel<<<N_NODES / RPB, 256, 0, stream>>>(
            W1 + (size_t)l * HIDDEN * HIDDEN, b1 + l * HIDDEN,
            W2 + (size_t)l * HIDDEN * HIDDEN, b2 + l * HIDDEN, h, z);
    }
    pool_kernel<<<N_GRAPHS, 256, 0, stream>>>(h, bid, gpool);
    head_kernel<<<N_GRAPHS, 256, 0, stream>>>(gpool, oW1, ob1, oW2, ob2, out);
}

// Round 4
// 894.886 us; speedup vs baseline: 2.0606x; 1.2401x over previous
//
#include <hip/hip_runtime.h>

#define N_NODES 20000
#define N_EDGES 320000
#define X_DIM 128
#define EDGE_DIM 64
#define HIDDEN 256
#define N_GRAPHS 64
#define LAYERS 3

#define NPB 8     // nodes per block (node_proj)
#define EB 32     // edges per tile (edge_mfma)
#define ET 4      // tiles per block (edge_mfma)
#define NBLK ((N_NODES + 255) / 256)   // 79 scan blocks

typedef __attribute__((ext_vector_type(8))) short short8;
typedef __attribute__((ext_vector_type(4))) float floatx4;

__device__ __forceinline__ unsigned short f2bf(float f) {
    union { float f; unsigned u; } v; v.f = f;
    return (unsigned short)((v.u + 0x7FFFu + ((v.u >> 16) & 1u)) >> 16);
}
__device__ __forceinline__ float bf2f(unsigned short u) {
    return __uint_as_float(((unsigned)u) << 16);
}

// ---------------- CSR build + pre-pass (once per launch) ----------------

__global__ __launch_bounds__(256) void deg_kernel(const int* __restrict__ ei,
                                                  int* __restrict__ deg)
{
    int e = blockIdx.x * 256 + threadIdx.x;
    if (e < N_EDGES) atomicAdd(&deg[ei[N_EDGES + e]], 1);
}

__global__ __launch_bounds__(256) void pscan_kernel(const int* __restrict__ deg,
                                                    int* __restrict__ rp,
                                                    int* __restrict__ bsum)
{
    __shared__ int buf[256];
    const int t = threadIdx.x;
    const int i = blockIdx.x * 256 + t;
    int v = (i < N_NODES) ? deg[i] : 0;
    buf[t] = v;
    __syncthreads();
    for (int off = 1; off < 256; off <<= 1) {
        int a = (t >= off) ? buf[t - off] : 0;
        __syncthreads();
        buf[t] += a;
        __syncthreads();
    }
    if (i < N_NODES) rp[i] = buf[t] - v;
    if (t == 255) bsum[blockIdx.x] = buf[255];
}

__global__ __launch_bounds__(128) void bscan_kernel(const int* __restrict__ bsum,
                                                    int* __restrict__ boff)
{
    __shared__ int buf[128];
    const int t = threadIdx.x;
    int v = (t < NBLK) ? bsum[t] : 0;
    buf[t] = v;
    __syncthreads();
    for (int off = 1; off < 128; off <<= 1) {
        int a = (t >= off) ? buf[t - off] : 0;
        __syncthreads();
        buf[t] += a;
        __syncthreads();
    }
    if (t < NBLK) boff[t] = buf[t] - v;
}

__global__ __launch_bounds__(256) void addoff_kernel(int* __restrict__ rp,
                                                     const int* __restrict__ boff)
{
    const int i = blockIdx.x * 256 + threadIdx.x;
    if (i < N_NODES) rp[i] += boff[blockIdx.x];
    if (i == 0) rp[N_NODES] = N_EDGES;
}

__global__ __launch_bounds__(256) void scatter_kernel(const int* __restrict__ ei,
                                                      const int* __restrict__ rp,
                                                      int* __restrict__ cursor,
                                                      int* __restrict__ perm)
{
    const int e = blockIdx.x * 256 + threadIdx.x;
    if (e < N_EDGES) {
        const int d = ei[N_EDGES + e];
        const int pos = atomicAdd(&cursor[d], 1);
        perm[rp[d] + pos] = e;
    }
}

// dst-sorted bf16 edge attrs + sorted src/dst index arrays
__global__ __launch_bounds__(256) void permute_kernel(
    const float* __restrict__ ea, const int* __restrict__ ei,
    const int* __restrict__ perm, unsigned short* __restrict__ eab,
    int* __restrict__ srcs, int* __restrict__ dsts)
{
    const int tid = blockIdx.x * 256 + threadIdx.x;
    const int e = tid >> 3, seg = tid & 7;
    const int p = perm[e];
    const float* sp = ea + (size_t)p * EDGE_DIM + seg * 8;
    const float4 v0 = *(const float4*)sp;
    const float4 v1 = *(const float4*)(sp + 4);
    short8 o;
    o[0] = (short)f2bf(v0.x); o[1] = (short)f2bf(v0.y);
    o[2] = (short)f2bf(v0.z); o[3] = (short)f2bf(v0.w);
    o[4] = (short)f2bf(v1.x); o[5] = (short)f2bf(v1.y);
    o[6] = (short)f2bf(v1.z); o[7] = (short)f2bf(v1.w);
    *(short8*)(eab + (size_t)e * EDGE_DIM + seg * 8) = o;
    if (seg == 0) { srcs[e] = ei[p]; dsts[e] = ei[N_EDGES + p]; }
}

// W [K][256] fp32 -> bf16 MFMA B-fragment order:
// out[((((wv*4+nt)*KK+kk)*64)+lane)*8+j] = W[(kk*32+(lane>>4)*8+j)*256 + wv*64+nt*16+(lane&15)]
__global__ __launch_bounds__(256) void swizzle_kernel(const float* __restrict__ W,
                                                      unsigned short* __restrict__ out,
                                                      int KK)
{
    const int i = blockIdx.x * 256 + threadIdx.x;
    if (i >= 8192 * KK) return;
    const int j = i & 7, lane = (i >> 3) & 63, rem = i >> 9;
    const int kk = rem % KK, rem2 = rem / KK, nt = rem2 & 3, wvv = rem2 >> 2;
    const int n = wvv * 64 + nt * 16 + (lane & 15);
    const int k = kk * 32 + (lane >> 4) * 8 + j;
    out[i] = f2bf(W[k * HIDDEN + n]);
}

// ---------------- model kernels ----------------

// h[i] = x[i] @ xW + xb (fp32); also writes hbf and zeroes z
__global__ __launch_bounds__(256) void node_proj_kernel(
    const float* __restrict__ x, const float* __restrict__ W,
    const float* __restrict__ b, float* __restrict__ h,
    unsigned short* __restrict__ hbf, float* __restrict__ z)
{
    const int t = threadIdx.x;
    const int row0 = blockIdx.x * NPB;
    __shared__ float xs[NPB][X_DIM];
    for (int idx = t; idx < NPB * X_DIM; idx += 256)
        xs[idx / X_DIM][idx % X_DIM] = x[(size_t)row0 * X_DIM + idx];
    __syncthreads();
    float acc[NPB];
    const float bt = b[t];
#pragma unroll
    for (int r = 0; r < NPB; r++) acc[r] = bt;
    for (int k = 0; k < X_DIM; k++) {
        const float wv = W[k * HIDDEN + t];
#pragma unroll
        for (int r = 0; r < NPB; r++) acc[r] += xs[r][k] * wv;
    }
#pragma unroll
    for (int r = 0; r < NPB; r++) {
        const size_t idx = (size_t)(row0 + r) * HIDDEN + t;
        h[idx] = acc[r];
        hbf[idx] = f2bf(acc[r]);
        z[idx] = 0.f;
    }
}

// edge phase: z[dst] += relu(hbf[src] + eab@eW + eb), edges dst-sorted.
// A,B frags straight from global (coalesced); segmented-sum epilogue.
__global__ __launch_bounds__(256) void edge_mfma_kernel(
    const unsigned short* __restrict__ eab, const int* __restrict__ srcs,
    const int* __restrict__ dsts, const unsigned short* __restrict__ Ws,
    const float* __restrict__ b, const unsigned short* __restrict__ hbf,
    float* __restrict__ z)
{
    const int t = threadIdx.x;
    const int lane = t & 63, wv = t >> 6, q = lane >> 4, m15 = lane & 15;
    __shared__ __align__(16) float msg[EB][264];
    __shared__ int s_src[EB], s_dst[EB];

    // loop-invariant B fragments (8 x 16B coalesced loads)
    short8 bfr[4][2];
#pragma unroll
    for (int nt = 0; nt < 4; nt++)
#pragma unroll
        for (int kk = 0; kk < 2; kk++)
            bfr[nt][kk] = *(const short8*)(Ws + ((((wv * 4 + nt) * 2 + kk) * 64) + lane) * 8);
    const float bt = b[t];

    for (int tile = 0; tile < ET; tile++) {
        const int e0 = (blockIdx.x * ET + tile) * EB;
        __syncthreads();  // protect s_src/s_dst/msg from previous epilogue
        if (t < EB) { s_src[t] = srcs[e0 + t]; s_dst[t] = dsts[e0 + t]; }

        floatx4 acc[2][4];
#pragma unroll
        for (int mt = 0; mt < 2; mt++)
#pragma unroll
            for (int nt = 0; nt < 4; nt++)
                acc[mt][nt] = (floatx4){0.f, 0.f, 0.f, 0.f};

#pragma unroll
        for (int kk = 0; kk < 2; kk++) {
            const short8 a0 = *(const short8*)(eab + (size_t)(e0 + m15) * EDGE_DIM + kk * 32 + q * 8);
            const short8 a1 = *(const short8*)(eab + (size_t)(e0 + 16 + m15) * EDGE_DIM + kk * 32 + q * 8);
#pragma unroll
            for (int nt = 0; nt < 4; nt++) {
                acc[0][nt] = __builtin_amdgcn_mfma_f32_16x16x32_bf16(a0, bfr[nt][kk], acc[0][nt], 0, 0, 0);
                acc[1][nt] = __builtin_amdgcn_mfma_f32_16x16x32_bf16(a1, bfr[nt][kk], acc[1][nt], 0, 0, 0);
            }
        }
        // C layout: edge = mt*16 + q*4 + r, ch = wv*64 + nt*16 + m15
#pragma unroll
        for (int mt = 0; mt < 2; mt++)
#pragma unroll
            for (int nt = 0; nt < 4; nt++)
#pragma unroll
                for (int r = 0; r < 4; r++)
                    msg[mt * 16 + q * 4 + r][wv * 64 + nt * 16 + m15] = acc[mt][nt][r];
        __syncthreads();

        // thread t owns channel t; segmented sum over sorted dst
        float s = 0.f;
        int prev = s_dst[0];
#pragma unroll
        for (int e = 0; e < EB; e++) {
            const int d = s_dst[e];
            if (d != prev) {
                atomicAdd(&z[(size_t)prev * HIDDEN + t], s);
                s = 0.f; prev = d;
            }
            const float hv = bf2f(hbf[(size_t)s_src[e] * HIDDEN + t]);
            const float m = msg[e][t] + bt + hv;
            s += m > 0.f ? m : 0.f;
        }
        atomicAdd(&z[(size_t)prev * HIDDEN + t], s);
    }
}

// h = relu(relu((h+z)@W1+b1)@W2+b2) with bf16 MFMA; re-zeroes z, writes hbf
__global__ __launch_bounds__(256) void mlp_mfma_kernel(
    const unsigned short* __restrict__ W1s, const float* __restrict__ b1,
    const unsigned short* __restrict__ W2s, const float* __restrict__ b2,
    float* __restrict__ h, float* __restrict__ z, unsigned short* __restrict__ hbf)
{
    const int t = threadIdx.x;
    const int lane = t & 63, wv = t >> 6, q = lane >> 4, m15 = lane & 15;
    const int row0 = blockIdx.x * 32;
    __shared__ __align__(16) unsigned short zs[32][264];

    // stage A = bf16(h+z); zero z for next layer
#pragma unroll
    for (int r = 0; r < 32; r++) {
        const size_t idx = (size_t)(row0 + r) * HIDDEN + t;
        zs[r][t] = f2bf(h[idx] + z[idx]);
        z[idx] = 0.f;
    }
    __syncthreads();

    float b1v[4], b2v[4];
#pragma unroll
    for (int nt = 0; nt < 4; nt++) {
        const int c = wv * 64 + nt * 16 + m15;
        b1v[nt] = b1[c]; b2v[nt] = b2[c];
    }

    floatx4 acc[2][4];
#pragma unroll
    for (int mt = 0; mt < 2; mt++)
#pragma unroll
        for (int nt = 0; nt < 4; nt++)
            acc[mt][nt] = (floatx4){0.f, 0.f, 0.f, 0.f};

    // GEMM1
#pragma unroll
    for (int kk = 0; kk < 8; kk++) {
        short8 bfr[4];
#pragma unroll
        for (int nt = 0; nt < 4; nt++)
            bfr[nt] = *(const short8*)(W1s + ((((wv * 4 + nt) * 8 + kk) * 64) + lane) * 8);
        const short8 a0 = *(const short8*)&zs[m15][kk * 32 + q * 8];
        const short8 a1 = *(const short8*)&zs[16 + m15][kk * 32 + q * 8];
#pragma unroll
        for (int nt = 0; nt < 4; nt++) {
            acc[0][nt] = __builtin_amdgcn_mfma_f32_16x16x32_bf16(a0, bfr[nt], acc[0][nt], 0, 0, 0);
            acc[1][nt] = __builtin_amdgcn_mfma_f32_16x16x32_bf16(a1, bfr[nt], acc[1][nt], 0, 0, 0);
        }
    }
    __syncthreads();
    // relu(acc+b1) -> zs (bf16)
#pragma unroll
    for (int mt = 0; mt < 2; mt++)
#pragma unroll
        for (int nt = 0; nt < 4; nt++)
#pragma unroll
            for (int r = 0; r < 4; r++) {
                const int row = mt * 16 + q * 4 + r, c = wv * 64 + nt * 16 + m15;
                const float v = acc[mt][nt][r] + b1v[nt];
                zs[row][c] = f2bf(v > 0.f ? v : 0.f);
            }
    __syncthreads();

#pragma unroll
    for (int mt = 0; mt < 2; mt++)
#pragma unroll
        for (int nt = 0; nt < 4; nt++)
            acc[mt][nt] = (floatx4){0.f, 0.f, 0.f, 0.f};

    // GEMM2
#pragma unroll
    for (int kk = 0; kk < 8; kk++) {
        short8 bfr[4];
#pragma unroll
        for (int nt = 0; nt < 4; nt++)
            bfr[nt] = *(const short8*)(W2s + ((((wv * 4 + nt) * 8 + kk) * 64) + lane) * 8);
        const short8 a0 = *(const short8*)&zs[m15][kk * 32 + q * 8];
        const short8 a1 = *(const short8*)&zs[16 + m15][kk * 32 + q * 8];
#pragma unroll
        for (int nt = 0; nt < 4; nt++) {
            acc[0][nt] = __builtin_amdgcn_mfma_f32_16x16x32_bf16(a0, bfr[nt], acc[0][nt], 0, 0, 0);
            acc[1][nt] = __builtin_amdgcn_mfma_f32_16x16x32_bf16(a1, bfr[nt], acc[1][nt], 0, 0, 0);
        }
    }
    // epilogue: h = relu(acc+b2), hbf = bf16(h)
#pragma unroll
    for (int mt = 0; mt < 2; mt++)
#pragma unroll
        for (int nt = 0; nt < 4; nt++)
#pragma unroll
            for (int r = 0; r < 4; r++) {
                const int row = mt * 16 + q * 4 + r, c = wv * 64 + nt * 16 + m15;
                float v = acc[mt][nt][r] + b2v[nt];
                v = v > 0.f ? v : 0.f;
                const size_t idx = (size_t)(row0 + row) * HIDDEN + c;
                h[idx] = v;
                hbf[idx] = f2bf(v);
            }
}

__global__ __launch_bounds__(256) void pool_kernel(
    const float* __restrict__ h, const int* __restrict__ bid,
    float* __restrict__ gout)
{
    const int g = blockIdx.x;
    const int t = threadIdx.x;
    int lo = 0, hi = N_NODES;
    while (lo < hi) { int mid = (lo + hi) >> 1; if (bid[mid] < g) lo = mid + 1; else hi = mid; }
    const int start = lo;
    hi = N_NODES;
    while (lo < hi) { int mid = (lo + hi) >> 1; if (bid[mid] < g + 1) lo = mid + 1; else hi = mid; }
    const int end = lo;
    float s = 0.f;
    for (int i = start; i < end; i++) s += h[(size_t)i * HIDDEN + t];
    const float cnt = (float)(end - start);
    gout[g * HIDDEN + t] = s / (cnt > 1.f ? cnt : 1.f);
}

__global__ __launch_bounds__(256) void head_kernel(
    const float* __restrict__ gin, const float* __restrict__ W1,
    const float* __restrict__ b1, const float* __restrict__ W2,
    const float* __restrict__ b2, float* __restrict__ out)
{
    const int g = blockIdx.x;
    const int t = threadIdx.x;
    __shared__ float gs[HIDDEN];
    __shared__ float t1[HIDDEN];
    __shared__ float red[256];
    gs[t] = gin[g * HIDDEN + t];
    __syncthreads();
    float acc = b1[t];
    for (int k = 0; k < HIDDEN; k++) acc += gs[k] * W1[k * HIDDEN + t];
    t1[t] = acc > 0.f ? acc : 0.f;
    __syncthreads();
    float acc2 = b2[t];
    for (int k = 0; k < HIDDEN; k++) acc2 += t1[k] * W2[k * HIDDEN + t];
    red[t] = acc2 * acc2;
    __syncthreads();
    for (int s = 128; s > 0; s >>= 1) {
        if (t < s) red[t] += red[t + s];
        __syncthreads();
    }
    float norm = sqrtf(red[0]);
    norm = norm > 1e-12f ? norm : 1e-12f;
    out[g * HIDDEN + t] = acc2 / norm;
}

extern "C" void kernel_launch(void* const* d_in, const int* in_sizes, int n_in,
                              void* d_out, int out_size, void* d_ws, size_t ws_size,
                              hipStream_t stream)
{
    const float* x   = (const float*)d_in[0];
    const int*   ei  = (const int*)d_in[1];
    const float* ea  = (const float*)d_in[2];
    const int*   bid = (const int*)d_in[3];
    const float* xW  = (const float*)d_in[4];
    const float* xb  = (const float*)d_in[5];
    const float* eW  = (const float*)d_in[6];
    const float* eb  = (const float*)d_in[7];
    const float* W1  = (const float*)d_in[8];
    const float* b1  = (const float*)d_in[9];
    const float* W2  = (const float*)d_in[10];
    const float* b2  = (const float*)d_in[11];
    const float* oW1 = (const float*)d_in[12];
    const float* ob1 = (const float*)d_in[13];
    const float* oW2 = (const float*)d_in[14];
    const float* ob2 = (const float*)d_in[15];
    float* out = (float*)d_out;

    // workspace layout (256B-aligned chunks)
    char* p = (char*)d_ws;
    auto alloc = [&](size_t bytes) { char* r = p; p += (bytes + 255) & ~(size_t)255; return r; };
    float* h     = (float*)alloc((size_t)N_NODES * HIDDEN * 4);
    float* z     = (float*)alloc((size_t)N_NODES * HIDDEN * 4);
    float* gpool = (float*)alloc((size_t)N_GRAPHS * HIDDEN * 4);
    int* deg     = (int*)alloc(N_NODES * 4);
    int* rowptr  = (int*)alloc((N_NODES + 1) * 4);
    int* cursor  = (int*)alloc(N_NODES * 4);
    int* bsum    = (int*)alloc(NBLK * 4);
    int* boff    = (int*)alloc(NBLK * 4);
    int* perm    = (int*)alloc((size_t)N_EDGES * 4);
    int* srcs    = (int*)alloc((size_t)N_EDGES * 4);
    int* dsts    = (int*)alloc((size_t)N_EDGES * 4);
    unsigned short* hbf = (unsigned short*)alloc((size_t)N_NODES * HIDDEN * 2);
    unsigned short* eab = (unsigned short*)alloc((size_t)N_EDGES * EDGE_DIM * 2);
    unsigned short* eWs = (unsigned short*)alloc((size_t)LAYERS * EDGE_DIM * HIDDEN * 2);
    unsigned short* W1s = (unsigned short*)alloc((size_t)LAYERS * HIDDEN * HIDDEN * 2);
    unsigned short* W2s = (unsigned short*)alloc((size_t)LAYERS * HIDDEN * HIDDEN * 2);

    // CSR build + dst-sorted bf16 edge data (reused across layers)
    hipMemsetAsync(deg, 0, N_NODES * sizeof(int), stream);
    hipMemsetAsync(cursor, 0, N_NODES * sizeof(int), stream);
    deg_kernel<<<(N_EDGES + 255) / 256, 256, 0, stream>>>(ei, deg);
    pscan_kernel<<<NBLK, 256, 0, stream>>>(deg, rowptr, bsum);
    bscan_kernel<<<1, 128, 0, stream>>>(bsum, boff);
    addoff_kernel<<<NBLK, 256, 0, stream>>>(rowptr, boff);
    scatter_kernel<<<(N_EDGES + 255) / 256, 256, 0, stream>>>(ei, rowptr, cursor, perm);
    permute_kernel<<<(N_EDGES * 8) / 256, 256, 0, stream>>>(ea, ei, perm, eab, srcs, dsts);
    for (int l = 0; l < LAYERS; l++) {
        swizzle_kernel<<<64, 256, 0, stream>>>(eW + (size_t)l * EDGE_DIM * HIDDEN,
                                               eWs + (size_t)l * EDGE_DIM * HIDDEN, 2);
        swizzle_kernel<<<256, 256, 0, stream>>>(W1 + (size_t)l * HIDDEN * HIDDEN,
                                                W1s + (size_t)l * HIDDEN * HIDDEN, 8);
        swizzle_kernel<<<256, 256, 0, stream>>>(W2 + (size_t)l * HIDDEN * HIDDEN,
                                                W2s + (size_t)l * HIDDEN * HIDDEN, 8);
    }

    node_proj_kernel<<<N_NODES / NPB, 256, 0, stream>>>(x, xW, xb, h, hbf, z);
    for (int l = 0; l < LAYERS; l++) {
        edge_mfma_kernel<<<N_EDGES / (EB * ET), 256, 0, stream>>>(
            eab, srcs, dsts, eWs + (size_t)l * EDGE_DIM * HIDDEN,
            eb + l * HIDDEN, hbf, z);
        mlp_mfma_kernel<<<N_NODES / 32, 256, 0, stream>>>(
            W1s + (size_t)l * HIDDEN * HIDDEN, b1 + l * HIDDEN,
            W2s + (size_t)l * HIDDEN * HIDDEN, b2 + l * HIDDEN, h, z, hbf);
    }
    pool_kernel<<<N_GRAPHS, 256, 0, stream>>>(h, bid, gpool);
    head_kernel<<<N_GRAPHS, 256, 0, stream>>>(gpool, oW1, ob1, oW2, ob2, out);
}

// Round 5
// 658.993 us; speedup vs baseline: 2.7982x; 1.3580x over previous
//
#include <hip/hip_runtime.h>

#define N_NODES 20000
#define N_EDGES 320000
#define X_DIM 128
#define EDGE_DIM 64
#define HIDDEN 256
#define N_GRAPHS 64
#define LAYERS 3

#define NPB 8     // nodes per block (node_proj)
#define EB 32     // edges per tile (edge_mfma)
#define ET 4      // tiles per block (edge_mfma)
#define NBLK ((N_NODES + 255) / 256)   // 79 scan blocks

typedef __attribute__((ext_vector_type(8))) short short8;
typedef __attribute__((ext_vector_type(4))) float floatx4;

__device__ __forceinline__ unsigned short f2bf(float f) {
    union { float f; unsigned u; } v; v.f = f;
    return (unsigned short)((v.u + 0x7FFFu + ((v.u >> 16) & 1u)) >> 16);
}
__device__ __forceinline__ float bf2f(unsigned short u) {
    return __uint_as_float(((unsigned)u) << 16);
}

// ---------------- CSR build + pre-pass (once per launch) ----------------

__global__ __launch_bounds__(256) void deg_kernel(const int* __restrict__ ei,
                                                  int* __restrict__ deg)
{
    int e = blockIdx.x * 256 + threadIdx.x;
    if (e < N_EDGES) atomicAdd(&deg[ei[N_EDGES + e]], 1);
}

__global__ __launch_bounds__(256) void pscan_kernel(const int* __restrict__ deg,
                                                    int* __restrict__ rp,
                                                    int* __restrict__ bsum)
{
    __shared__ int buf[256];
    const int t = threadIdx.x;
    const int i = blockIdx.x * 256 + t;
    int v = (i < N_NODES) ? deg[i] : 0;
    buf[t] = v;
    __syncthreads();
    for (int off = 1; off < 256; off <<= 1) {
        int a = (t >= off) ? buf[t - off] : 0;
        __syncthreads();
        buf[t] += a;
        __syncthreads();
    }
    if (i < N_NODES) rp[i] = buf[t] - v;
    if (t == 255) bsum[blockIdx.x] = buf[255];
}

__global__ __launch_bounds__(128) void bscan_kernel(const int* __restrict__ bsum,
                                                    int* __restrict__ boff)
{
    __shared__ int buf[128];
    const int t = threadIdx.x;
    int v = (t < NBLK) ? bsum[t] : 0;
    buf[t] = v;
    __syncthreads();
    for (int off = 1; off < 128; off <<= 1) {
        int a = (t >= off) ? buf[t - off] : 0;
        __syncthreads();
        buf[t] += a;
        __syncthreads();
    }
    if (t < NBLK) boff[t] = buf[t] - v;
}

__global__ __launch_bounds__(256) void addoff_kernel(int* __restrict__ rp,
                                                     const int* __restrict__ boff)
{
    const int i = blockIdx.x * 256 + threadIdx.x;
    if (i < N_NODES) rp[i] += boff[blockIdx.x];
    if (i == 0) rp[N_NODES] = N_EDGES;
}

__global__ __launch_bounds__(256) void scatter_kernel(const int* __restrict__ ei,
                                                      const int* __restrict__ rp,
                                                      int* __restrict__ cursor,
                                                      int* __restrict__ perm)
{
    const int e = blockIdx.x * 256 + threadIdx.x;
    if (e < N_EDGES) {
        const int d = ei[N_EDGES + e];
        const int pos = atomicAdd(&cursor[d], 1);
        perm[rp[d] + pos] = e;
    }
}

// dst-sorted bf16 edge attrs + sorted src/dst index arrays
__global__ __launch_bounds__(256) void permute_kernel(
    const float* __restrict__ ea, const int* __restrict__ ei,
    const int* __restrict__ perm, unsigned short* __restrict__ eab,
    int* __restrict__ srcs, int* __restrict__ dsts)
{
    const int tid = blockIdx.x * 256 + threadIdx.x;
    const int e = tid >> 3, seg = tid & 7;
    const int p = perm[e];
    const float* sp = ea + (size_t)p * EDGE_DIM + seg * 8;
    const float4 v0 = *(const float4*)sp;
    const float4 v1 = *(const float4*)(sp + 4);
    short8 o;
    o[0] = (short)f2bf(v0.x); o[1] = (short)f2bf(v0.y);
    o[2] = (short)f2bf(v0.z); o[3] = (short)f2bf(v0.w);
    o[4] = (short)f2bf(v1.x); o[5] = (short)f2bf(v1.y);
    o[6] = (short)f2bf(v1.z); o[7] = (short)f2bf(v1.w);
    *(short8*)(eab + (size_t)e * EDGE_DIM + seg * 8) = o;
    if (seg == 0) { srcs[e] = ei[p]; dsts[e] = ei[N_EDGES + p]; }
}

// W [K][256] fp32 -> bf16 MFMA B-fragment order
__global__ __launch_bounds__(256) void swizzle_kernel(const float* __restrict__ W,
                                                      unsigned short* __restrict__ out,
                                                      int KK)
{
    const int i = blockIdx.x * 256 + threadIdx.x;
    if (i >= 8192 * KK) return;
    const int j = i & 7, lane = (i >> 3) & 63, rem = i >> 9;
    const int kk = rem % KK, rem2 = rem / KK, nt = rem2 & 3, wvv = rem2 >> 2;
    const int n = wvv * 64 + nt * 16 + (lane & 15);
    const int k = kk * 32 + (lane >> 4) * 8 + j;
    out[i] = f2bf(W[k * HIDDEN + n]);
}

// ---------------- model kernels ----------------

// h[i] = x[i] @ xW + xb (fp32); also writes hbf and zeroes z
__global__ __launch_bounds__(256) void node_proj_kernel(
    const float* __restrict__ x, const float* __restrict__ W,
    const float* __restrict__ b, float* __restrict__ h,
    unsigned short* __restrict__ hbf, float* __restrict__ z)
{
    const int t = threadIdx.x;
    const int row0 = blockIdx.x * NPB;
    __shared__ float xs[NPB][X_DIM];
    for (int idx = t; idx < NPB * X_DIM; idx += 256)
        xs[idx / X_DIM][idx % X_DIM] = x[(size_t)row0 * X_DIM + idx];
    __syncthreads();
    float acc[NPB];
    const float bt = b[t];
#pragma unroll
    for (int r = 0; r < NPB; r++) acc[r] = bt;
    for (int k = 0; k < X_DIM; k++) {
        const float wv = W[k * HIDDEN + t];
#pragma unroll
        for (int r = 0; r < NPB; r++) acc[r] += xs[r][k] * wv;
    }
#pragma unroll
    for (int r = 0; r < NPB; r++) {
        const size_t idx = (size_t)(row0 + r) * HIDDEN + t;
        h[idx] = acc[r];
        hbf[idx] = f2bf(acc[r]);
        z[idx] = 0.f;
    }
}

// edge phase: z[dst] += relu(hbf[src] + eab@eW + eb), edges dst-sorted.
// hv register-prefetched per tile; double-buffered index arrays.
__global__ __launch_bounds__(256) void edge_mfma_kernel(
    const unsigned short* __restrict__ eab, const int* __restrict__ srcs,
    const int* __restrict__ dsts, const unsigned short* __restrict__ Ws,
    const float* __restrict__ b, const unsigned short* __restrict__ hbf,
    float* __restrict__ z)
{
    const int t = threadIdx.x;
    const int lane = t & 63, wv = t >> 6, q = lane >> 4, m15 = lane & 15;
    __shared__ __align__(16) float msg[EB][260];   // 260: 4-bank row offset -> 2-way max
    __shared__ int s_src[2][EB], s_dst[2][EB];

    // loop-invariant B fragments (8 x 16B coalesced loads)
    short8 bfr[4][2];
#pragma unroll
    for (int nt = 0; nt < 4; nt++)
#pragma unroll
        for (int kk = 0; kk < 2; kk++)
            bfr[nt][kk] = *(const short8*)(Ws + ((((wv * 4 + nt) * 2 + kk) * 64) + lane) * 8);
    const float bt = b[t];

    // preload tile 0 indices
    if (t < EB) {
        const int e0 = blockIdx.x * ET * EB;
        s_src[0][t] = srcs[e0 + t];
        s_dst[0][t] = dsts[e0 + t];
    }
    __syncthreads();

    for (int tile = 0; tile < ET; tile++) {
        const int cur = tile & 1;
        const int e0 = (blockIdx.x * ET + tile) * EB;

        // 1. prefetch h rows for this tile into registers (32 loads in flight,
        //    latency hidden under MFMA + msg write + barrier)
        unsigned short hv[EB];
#pragma unroll
        for (int e = 0; e < EB; e++)
            hv[e] = hbf[(size_t)s_src[cur][e] * HIDDEN + t];

        // 2. prefetch next tile's indices into the other buffer
        if (tile + 1 < ET && t < EB) {
            s_src[1 - cur][t] = srcs[e0 + EB + t];
            s_dst[1 - cur][t] = dsts[e0 + EB + t];
        }

        // 3. MFMA: proj = eab[tile] @ eW
        floatx4 acc[2][4];
#pragma unroll
        for (int mt = 0; mt < 2; mt++)
#pragma unroll
            for (int nt = 0; nt < 4; nt++)
                acc[mt][nt] = (floatx4){0.f, 0.f, 0.f, 0.f};
#pragma unroll
        for (int kk = 0; kk < 2; kk++) {
            const short8 a0 = *(const short8*)(eab + (size_t)(e0 + m15) * EDGE_DIM + kk * 32 + q * 8);
            const short8 a1 = *(const short8*)(eab + (size_t)(e0 + 16 + m15) * EDGE_DIM + kk * 32 + q * 8);
#pragma unroll
            for (int nt = 0; nt < 4; nt++) {
                acc[0][nt] = __builtin_amdgcn_mfma_f32_16x16x32_bf16(a0, bfr[nt][kk], acc[0][nt], 0, 0, 0);
                acc[1][nt] = __builtin_amdgcn_mfma_f32_16x16x32_bf16(a1, bfr[nt][kk], acc[1][nt], 0, 0, 0);
            }
        }
        // C layout: edge = mt*16 + q*4 + r, ch = wv*64 + nt*16 + m15
#pragma unroll
        for (int mt = 0; mt < 2; mt++)
#pragma unroll
            for (int nt = 0; nt < 4; nt++)
#pragma unroll
                for (int r = 0; r < 4; r++)
                    msg[mt * 16 + q * 4 + r][wv * 64 + nt * 16 + m15] = acc[mt][nt][r];
        __syncthreads();

        // 4. epilogue: thread t owns channel t; segmented sum over sorted dst
        float s = 0.f;
        int prev = s_dst[cur][0];
#pragma unroll
        for (int e = 0; e < EB; e++) {
            const int d = s_dst[cur][e];
            if (d != prev) {
                atomicAdd(&z[(size_t)prev * HIDDEN + t], s);
                s = 0.f; prev = d;
            }
            const float m = msg[e][t] + bt + bf2f(hv[e]);
            s += m > 0.f ? m : 0.f;
        }
        atomicAdd(&z[(size_t)prev * HIDDEN + t], s);
        __syncthreads();   // msg/s_dst reuse next tile
    }
}

// h = relu(relu((h+z)@W1+b1)@W2+b2) with bf16 MFMA; re-zeroes z, writes hbf
__global__ __launch_bounds__(256) void mlp_mfma_kernel(
    const unsigned short* __restrict__ W1s, const float* __restrict__ b1,
    const unsigned short* __restrict__ W2s, const float* __restrict__ b2,
    float* __restrict__ h, float* __restrict__ z, unsigned short* __restrict__ hbf)
{
    const int t = threadIdx.x;
    const int lane = t & 63, wv = t >> 6, q = lane >> 4, m15 = lane & 15;
    const int row0 = blockIdx.x * 32;
    __shared__ __align__(16) unsigned short zs[32][264];

    // stage A = bf16(h+z); zero z for next layer
#pragma unroll
    for (int r = 0; r < 32; r++) {
        const size_t idx = (size_t)(row0 + r) * HIDDEN + t;
        zs[r][t] = f2bf(h[idx] + z[idx]);
        z[idx] = 0.f;
    }
    __syncthreads();

    float b1v[4], b2v[4];
#pragma unroll
    for (int nt = 0; nt < 4; nt++) {
        const int c = wv * 64 + nt * 16 + m15;
        b1v[nt] = b1[c]; b2v[nt] = b2[c];
    }

    floatx4 acc[2][4];
#pragma unroll
    for (int mt = 0; mt < 2; mt++)
#pragma unroll
        for (int nt = 0; nt < 4; nt++)
            acc[mt][nt] = (floatx4){0.f, 0.f, 0.f, 0.f};

    // GEMM1
#pragma unroll
    for (int kk = 0; kk < 8; kk++) {
        short8 bfr[4];
#pragma unroll
        for (int nt = 0; nt < 4; nt++)
            bfr[nt] = *(const short8*)(W1s + ((((wv * 4 + nt) * 8 + kk) * 64) + lane) * 8);
        const short8 a0 = *(const short8*)&zs[m15][kk * 32 + q * 8];
        const short8 a1 = *(const short8*)&zs[16 + m15][kk * 32 + q * 8];
#pragma unroll
        for (int nt = 0; nt < 4; nt++) {
            acc[0][nt] = __builtin_amdgcn_mfma_f32_16x16x32_bf16(a0, bfr[nt], acc[0][nt], 0, 0, 0);
            acc[1][nt] = __builtin_amdgcn_mfma_f32_16x16x32_bf16(a1, bfr[nt], acc[1][nt], 0, 0, 0);
        }
    }
    __syncthreads();
    // relu(acc+b1) -> zs (bf16)
#pragma unroll
    for (int mt = 0; mt < 2; mt++)
#pragma unroll
        for (int nt = 0; nt < 4; nt++)
#pragma unroll
            for (int r = 0; r < 4; r++) {
                const int row = mt * 16 + q * 4 + r, c = wv * 64 + nt * 16 + m15;
                const float v = acc[mt][nt][r] + b1v[nt];
                zs[row][c] = f2bf(v > 0.f ? v : 0.f);
            }
    __syncthreads();

#pragma unroll
    for (int mt = 0; mt < 2; mt++)
#pragma unroll
        for (int nt = 0; nt < 4; nt++)
            acc[mt][nt] = (floatx4){0.f, 0.f, 0.f, 0.f};

    // GEMM2
#pragma unroll
    for (int kk = 0; kk < 8; kk++) {
        short8 bfr[4];
#pragma unroll
        for (int nt = 0; nt < 4; nt++)
            bfr[nt] = *(const short8*)(W2s + ((((wv * 4 + nt) * 8 + kk) * 64) + lane) * 8);
        const short8 a0 = *(const short8*)&zs[m15][kk * 32 + q * 8];
        const short8 a1 = *(const short8*)&zs[16 + m15][kk * 32 + q * 8];
#pragma unroll
        for (int nt = 0; nt < 4; nt++) {
            acc[0][nt] = __builtin_amdgcn_mfma_f32_16x16x32_bf16(a0, bfr[nt], acc[0][nt], 0, 0, 0);
            acc[1][nt] = __builtin_amdgcn_mfma_f32_16x16x32_bf16(a1, bfr[nt], acc[1][nt], 0, 0, 0);
        }
    }
    // epilogue: h = relu(acc+b2), hbf = bf16(h)
#pragma unroll
    for (int mt = 0; mt < 2; mt++)
#pragma unroll
        for (int nt = 0; nt < 4; nt++)
#pragma unroll
            for (int r = 0; r < 4; r++) {
                const int row = mt * 16 + q * 4 + r, c = wv * 64 + nt * 16 + m15;
                float v = acc[mt][nt][r] + b2v[nt];
                v = v > 0.f ? v : 0.f;
                const size_t idx = (size_t)(row0 + row) * HIDDEN + c;
                h[idx] = v;
                hbf[idx] = f2bf(v);
            }
}

__global__ __launch_bounds__(256) void pool_kernel(
    const float* __restrict__ h, const int* __restrict__ bid,
    float* __restrict__ gout)
{
    const int g = blockIdx.x;
    const int t = threadIdx.x;
    int lo = 0, hi = N_NODES;
    while (lo < hi) { int mid = (lo + hi) >> 1; if (bid[mid] < g) lo = mid + 1; else hi = mid; }
    const int start = lo;
    hi = N_NODES;
    while (lo < hi) { int mid = (lo + hi) >> 1; if (bid[mid] < g + 1) lo = mid + 1; else hi = mid; }
    const int end = lo;
    float s = 0.f;
    for (int i = start; i < end; i++) s += h[(size_t)i * HIDDEN + t];
    const float cnt = (float)(end - start);
    gout[g * HIDDEN + t] = s / (cnt > 1.f ? cnt : 1.f);
}

__global__ __launch_bounds__(256) void head_kernel(
    const float* __restrict__ gin, const float* __restrict__ W1,
    const float* __restrict__ b1, const float* __restrict__ W2,
    const float* __restrict__ b2, float* __restrict__ out)
{
    const int g = blockIdx.x;
    const int t = threadIdx.x;
    __shared__ float gs[HIDDEN];
    __shared__ float t1[HIDDEN];
    __shared__ float red[256];
    gs[t] = gin[g * HIDDEN + t];
    __syncthreads();
    float acc = b1[t];
    for (int k = 0; k < HIDDEN; k++) acc += gs[k] * W1[k * HIDDEN + t];
    t1[t] = acc > 0.f ? acc : 0.f;
    __syncthreads();
    float acc2 = b2[t];
    for (int k = 0; k < HIDDEN; k++) acc2 += t1[k] * W2[k * HIDDEN + t];
    red[t] = acc2 * acc2;
    __syncthreads();
    for (int s = 128; s > 0; s >>= 1) {
        if (t < s) red[t] += red[t + s];
        __syncthreads();
    }
    float norm = sqrtf(red[0]);
    norm = norm > 1e-12f ? norm : 1e-12f;
    out[g * HIDDEN + t] = acc2 / norm;
}

extern "C" void kernel_launch(void* const* d_in, const int* in_sizes, int n_in,
                              void* d_out, int out_size, void* d_ws, size_t ws_size,
                              hipStream_t stream)
{
    const float* x   = (const float*)d_in[0];
    const int*   ei  = (const int*)d_in[1];
    const float* ea  = (const float*)d_in[2];
    const int*   bid = (const int*)d_in[3];
    const float* xW  = (const float*)d_in[4];
    const float* xb  = (const float*)d_in[5];
    const float* eW  = (const float*)d_in[6];
    const float* eb  = (const float*)d_in[7];
    const float* W1  = (const float*)d_in[8];
    const float* b1  = (const float*)d_in[9];
    const float* W2  = (const float*)d_in[10];
    const float* b2  = (const float*)d_in[11];
    const float* oW1 = (const float*)d_in[12];
    const float* ob1 = (const float*)d_in[13];
    const float* oW2 = (const float*)d_in[14];
    const float* ob2 = (const float*)d_in[15];
    float* out = (float*)d_out;

    // workspace layout (256B-aligned chunks)
    char* p = (char*)d_ws;
    auto alloc = [&](size_t bytes) { char* r = p; p += (bytes + 255) & ~(size_t)255; return r; };
    float* h     = (float*)alloc((size_t)N_NODES * HIDDEN * 4);
    float* z     = (float*)alloc((size_t)N_NODES * HIDDEN * 4);
    float* gpool = (float*)alloc((size_t)N_GRAPHS * HIDDEN * 4);
    int* deg     = (int*)alloc(N_NODES * 4);
    int* rowptr  = (int*)alloc((N_NODES + 1) * 4);
    int* cursor  = (int*)alloc(N_NODES * 4);
    int* bsum    = (int*)alloc(NBLK * 4);
    int* boff    = (int*)alloc(NBLK * 4);
    int* perm    = (int*)alloc((size_t)N_EDGES * 4);
    int* srcs    = (int*)alloc((size_t)N_EDGES * 4);
    int* dsts    = (int*)alloc((size_t)N_EDGES * 4);
    unsigned short* hbf = (unsigned short*)alloc((size_t)N_NODES * HIDDEN * 2);
    unsigned short* eab = (unsigned short*)alloc((size_t)N_EDGES * EDGE_DIM * 2);
    unsigned short* eWs = (unsigned short*)alloc((size_t)LAYERS * EDGE_DIM * HIDDEN * 2);
    unsigned short* W1s = (unsigned short*)alloc((size_t)LAYERS * HIDDEN * HIDDEN * 2);
    unsigned short* W2s = (unsigned short*)alloc((size_t)LAYERS * HIDDEN * HIDDEN * 2);

    // CSR build + dst-sorted bf16 edge data (reused across layers)
    hipMemsetAsync(deg, 0, N_NODES * sizeof(int), stream);
    hipMemsetAsync(cursor, 0, N_NODES * sizeof(int), stream);
    deg_kernel<<<(N_EDGES + 255) / 256, 256, 0, stream>>>(ei, deg);
    pscan_kernel<<<NBLK, 256, 0, stream>>>(deg, rowptr, bsum);
    bscan_kernel<<<1, 128, 0, stream>>>(bsum, boff);
    addoff_kernel<<<NBLK, 256, 0, stream>>>(rowptr, boff);
    scatter_kernel<<<(N_EDGES + 255) / 256, 256, 0, stream>>>(ei, rowptr, cursor, perm);
    permute_kernel<<<(N_EDGES * 8) / 256, 256, 0, stream>>>(ea, ei, perm, eab, srcs, dsts);
    for (int l = 0; l < LAYERS; l++) {
        swizzle_kernel<<<64, 256, 0, stream>>>(eW + (size_t)l * EDGE_DIM * HIDDEN,
                                               eWs + (size_t)l * EDGE_DIM * HIDDEN, 2);
        swizzle_kernel<<<256, 256, 0, stream>>>(W1 + (size_t)l * HIDDEN * HIDDEN,
                                                W1s + (size_t)l * HIDDEN * HIDDEN, 8);
        swizzle_kernel<<<256, 256, 0, stream>>>(W2 + (size_t)l * HIDDEN * HIDDEN,
                                                W2s + (size_t)l * HIDDEN * HIDDEN, 8);
    }

    node_proj_kernel<<<N_NODES / NPB, 256, 0, stream>>>(x, xW, xb, h, hbf, z);
    for (int l = 0; l < LAYERS; l++) {
        edge_mfma_kernel<<<N_EDGES / (EB * ET), 256, 0, stream>>>(
            eab, srcs, dsts, eWs + (size_t)l * EDGE_DIM * HIDDEN,
            eb + l * HIDDEN, hbf, z);
        mlp_mfma_kernel<<<N_NODES / 32, 256, 0, stream>>>(
            W1s + (size_t)l * HIDDEN * HIDDEN, b1 + l * HIDDEN,
            W2s + (size_t)l * HIDDEN * HIDDEN, b2 + l * HIDDEN, h, z, hbf);
    }
    pool_kernel<<<N_GRAPHS, 256, 0, stream>>>(h, bid, gpool);
    head_kernel<<<N_GRAPHS, 256, 0, stream>>>(gpool, oW1, ob1, oW2, ob2, out);
}